// Round 1
// baseline (230.181 us; speedup 1.0000x reference)
//
#include <hip/hip_runtime.h>

#define NBINS 256
#define NCH 3
#define NHIST (2 * NCH * NBINS)   // 1536 global bins (input + label)
#define BATCH 32
#define THREADS 128
#define BLOCKS_PER_JOB 512         // 512 blk * 128 thr = 65536 threads = HW4 exactly

// ===========================================================================
// R8: ping-pong dual LDS histograms per wave + software-pipelined quad stream.
// Theory: the ~240 cyc/batch4 cost of the R3 kernel is NOT an intrinsic
// "30 cyc scattered-op" pipe floor but the lgkmcnt(0) round-trip per quad
// (in-order retirement forces each quad's read-wait to also drain the prior
// quad's writes) plus potential W->R same-region hazards. Alternating quads
// between two disjoint 16 KB regions (A/B) per wave means:
//   - a quad's ds_reads never alias the immediately preceding ds_writes
//   - the wait for quad k's reads is issued 8 DS-ops downstream (compiler
//     emits counted lgkmcnt), so write retirement is never on the wave's
//     critical path.
// Op count unchanged (2 scattered DS ops/element). Correctness of same-region
// W->R across non-adjacent quads relies on same-wave program-order DS
// completion (same guarantee the R3 kernel verified, absmax=0).
// Per-region max count/thread = 16 float4 * 4 = 64 < 255: u8 safe.
// ===========================================================================

struct Quad {
    unsigned int* p0; unsigned int* p1; unsigned int* p2; unsigned int* p3;
    unsigned int r0, r1, r2, r3;
    unsigned int i0, i1, i2, i3;
    int w0, w1, w2, w3;
};

__device__ __forceinline__ void quad_read(unsigned int* lbase, float4 v, Quad& q) {
    const int b0 = (int)fminf(fmaxf(v.x, 0.f), 255.f);  // trunc==floor, v>=0
    const int b1 = (int)fminf(fmaxf(v.y, 0.f), 255.f);
    const int b2 = (int)fminf(fmaxf(v.z, 0.f), 255.f);
    const int b3 = (int)fminf(fmaxf(v.w, 0.f), 255.f);
    q.w0 = b0 >> 2; q.w1 = b1 >> 2; q.w2 = b2 >> 2; q.w3 = b3 >> 2;
    q.i0 = 1u << ((b0 & 3) << 3);
    q.i1 = 1u << ((b1 & 3) << 3);
    q.i2 = 1u << ((b2 & 3) << 3);
    q.i3 = 1u << ((b3 & 3) << 3);
    q.p0 = lbase + q.w0 * 64;
    q.p1 = lbase + q.w1 * 64;
    q.p2 = lbase + q.w2 * 64;
    q.p3 = lbase + q.w3 * 64;
    q.r0 = *q.p0;   // 4 scattered ds_reads, bank = lane&31 (conflict-free)
    q.r1 = *q.p1;
    q.r2 = *q.p2;
    q.r3 = *q.p3;
}

__device__ __forceinline__ void quad_write(Quad& q) {
    // register dedup: same-word duplicates forward-merge into highest slot;
    // stale earlier write is overwritten by the later full write (same-wave
    // DS ops to one address complete in program order).
    if (q.w0 == q.w1) { q.i1 += q.i0; q.i0 = 0; }
    if (q.w0 == q.w2) { q.i2 += q.i0; q.i0 = 0; }
    if (q.w0 == q.w3) { q.i3 += q.i0; q.i0 = 0; }
    if (q.w1 == q.w2) { q.i2 += q.i1; q.i1 = 0; }
    if (q.w1 == q.w3) { q.i3 += q.i1; q.i1 = 0; }
    if (q.w2 == q.w3) { q.i3 += q.i2; q.i2 = 0; }
    *q.p0 = q.r0 + q.i0;
    *q.p1 = q.r1 + q.i1;
    *q.p2 = q.r2 + q.i2;
    *q.p3 = q.r3 + q.i3;
}

__global__ __launch_bounds__(THREADS) void hist_kernel(
    const float* __restrict__ a, const float* __restrict__ b,
    unsigned int* __restrict__ gh) {
    // 2 waves x 2 regions x 4096 words x 4B = 64 KB -> 2 blocks/CU
    __shared__ unsigned int sh[16384];
    const int tid  = threadIdx.x;
    const int wave = tid >> 6;
    const int lane = tid & 63;

    uint4* shv = (uint4*)sh;
    #pragma unroll
    for (int i = 0; i < 32; ++i)
        shv[tid + i * THREADS] = make_uint4(0u, 0u, 0u, 0u);
    __syncthreads();

    const int job        = blockIdx.x >> 9;        // 0..5
    const int blockInJob = blockIdx.x & 511;
    const int arr = job / NCH;   // 0 = input, 1 = label
    const int ch  = job % NCH;

    const float4* __restrict__ src = (const float4*)(arr ? b : a);
    // word = wave*8192 + reg*4096 + (bin>>2)*64 + lane -> bank = lane&31
    unsigned int* const baseA = &sh[wave * 8192 + lane];
    unsigned int* const baseB = baseA + 4096;
    const unsigned pos = ((unsigned)blockInJob << 7) | (unsigned)tid;  // 0..65535

#define LOADIDX(bt) ((unsigned)((((bt) * NCH + ch) << 16) | pos))

    // 8-deep global prefetch; next group's loads issued before processing
    // the current group so HBM latency hides under DS/VALU work.
    float4 c0 = src[LOADIDX(0)], c1 = src[LOADIDX(1)];
    float4 c2 = src[LOADIDX(2)], c3 = src[LOADIDX(3)];
    float4 c4 = src[LOADIDX(4)], c5 = src[LOADIDX(5)];
    float4 c6 = src[LOADIDX(6)], c7 = src[LOADIDX(7)];

    #pragma unroll
    for (int it = 0; it < BATCH / 8; ++it) {
        float4 n0, n1, n2, n3, n4, n5, n6, n7;
        if (it < 3) {
            const int nbt = (it + 1) << 3;
            n0 = src[LOADIDX(nbt + 0)]; n1 = src[LOADIDX(nbt + 1)];
            n2 = src[LOADIDX(nbt + 2)]; n3 = src[LOADIDX(nbt + 3)];
            n4 = src[LOADIDX(nbt + 4)]; n5 = src[LOADIDX(nbt + 5)];
            n6 = src[LOADIDX(nbt + 6)]; n7 = src[LOADIDX(nbt + 7)];
        }
        Quad qa, qb;
        // ping-pong pipeline: reads of the next quad are issued before the
        // wait/writes of the previous quad's partner region.
        quad_read(baseA, c0, qa);
        quad_read(baseB, c1, qb);
        quad_write(qa); quad_read(baseA, c2, qa);
        quad_write(qb); quad_read(baseB, c3, qb);
        quad_write(qa); quad_read(baseA, c4, qa);
        quad_write(qb); quad_read(baseB, c5, qb);
        quad_write(qa); quad_read(baseA, c6, qa);
        quad_write(qb); quad_read(baseB, c7, qb);
        quad_write(qa);
        quad_write(qb);
        if (it < 3) {
            c0 = n0; c1 = n1; c2 = n2; c3 = n3;
            c4 = n4; c5 = n5; c6 = n6; c7 = n7;
        }
    }
    __syncthreads();

    // Flush: 128 threads x 2 bins each (t, t+128). Sum the bin's byte over
    // 4 region-stripes x 64 lanes, uint4 reads, chunk-swizzled (cc) to
    // spread banks (pattern carried over from R3, measured 0 conflicts).
    #pragma unroll
    for (int h = 0; h < 2; ++h) {
        const int bin = tid + (h << 7);
        const int grp = bin >> 2;
        const int sh8 = (bin & 3) << 3;
        unsigned int s = 0;
        #pragma unroll
        for (int wr = 0; wr < 4; ++wr) {   // wave*2 + region
            const unsigned int* base = &sh[wr * 4096 + grp * 64];
            #pragma unroll
            for (int c = 0; c < 16; ++c) {
                const int cc = (c + tid) & 15;
                const uint4 q = *(const uint4*)(base + cc * 4);
                s += ((q.x >> sh8) & 0xFFu) + ((q.y >> sh8) & 0xFFu)
                   + ((q.z >> sh8) & 0xFFu) + ((q.w >> sh8) & 0xFFu);
            }
        }
        atomicAdd(&gh[(arr * NCH + ch) * NBINS + bin], s);
    }
}

// ---------------------------------------------------------------------------
// Bhattacharyya kernel: 1 block x 256 threads, fp64 reduction. (unchanged)
// ---------------------------------------------------------------------------
__device__ __forceinline__ double block_reduce256(double v, double* sh4) {
    const int t = threadIdx.x;
    const int lane = t & 63, w = t >> 6;
    #pragma unroll
    for (int o = 32; o > 0; o >>= 1) v += __shfl_down(v, o, 64);
    if (lane == 0) sh4[w] = v;
    __syncthreads();
    double r = sh4[0] + sh4[1] + sh4[2] + sh4[3];
    __syncthreads();
    return r;
}

__global__ __launch_bounds__(256) void bhat_kernel(
    const unsigned int* __restrict__ gh, float* __restrict__ out) {
    __shared__ double sh4[4];
    const int t = threadIdx.x;  // bin index
    double result = 0.0;
    #pragma unroll
    for (int ch = 0; ch < NCH; ++ch) {
        const double h1 = (double)gh[ch * NBINS + t];
        const double h2 = (double)gh[(NCH + ch) * NBINS + t];
        const double s  = block_reduce256(sqrt(h1 * h2), sh4);
        const double s1 = block_reduce256(h1, sh4);
        const double s2 = block_reduce256(h2, sh4);
        const double denom = sqrt((s1 / (double)NBINS) * (s2 / (double)NBINS)) * (double)NBINS;
        const double v = 1.0 - s / denom;
        result += sqrt(v > 0.0 ? v : 0.0);
    }
    if (t == 0) out[0] = (float)result;
}

extern "C" void kernel_launch(void* const* d_in, const int* in_sizes, int n_in,
                              void* d_out, int out_size, void* d_ws, size_t ws_size,
                              hipStream_t stream) {
    const float* input = (const float*)d_in[0];
    const float* label = (const float*)d_in[1];
    float* out = (float*)d_out;
    unsigned int* gh = (unsigned int*)d_ws;

    // d_ws is poisoned with 0xAA before every timed launch — zero the hists.
    hipMemsetAsync(gh, 0, NHIST * sizeof(unsigned int), stream);

    hist_kernel<<<6 * BLOCKS_PER_JOB, THREADS, 0, stream>>>(input, label, gh);
    bhat_kernel<<<1, 256, 0, stream>>>(gh, out);
}

// Round 3
// 227.935 us; speedup vs baseline: 1.0099x; 1.0099x over previous
//
#include <hip/hip_runtime.h>

#define NBINS 256
#define NCH 3
#define NHIST (2 * NCH * NBINS)   // 1536 global bins (input + label)
#define HW4 65536                  // 512*512/4 float4s per (batch,channel) plane
#define BATCH 32
#define BLOCKS_PER_JOB 256         // 256 blk * 256 thr = 65536 threads = HW4 exactly
#define THREADS 256

// ===========================================================================
// R10 (= R9 retry; R9 bench died to infra, not the kernel).
// R3 structure (256 thr, 8 waves/CU — saturates the LDS pipe per R7/R8
// evidence) + dedup window widened 4 -> 16 elements.
// Model: LDS pipe saturated at ~30 cyc per scattered-address wave-op
// (R7: 2x waves same time; R8: 0.5x waves +21% time). VALU at 25% has
// headroom. Widening the register dedup window removes whole wave-ops:
// E[distinct 4-bin words among 16 uniform elements] = 64*(1-(63/64)^16)
// = 14.25 vs 15.6 for 4-wide windows -> ~9% fewer scattered DS ops at the
// cost of ~120 pair-compares (VALU). Duplicate-word writes within a window
// rely on same-wave program-order DS completion (verified absmax=0 in R3).
// Per-thread per-bin count <= 128 < 255: u8 counters safe.
// vs R9 draft: word-offsets (int) instead of pointer array — halves live
// address VGPRs; all array indexing compile-time (full unroll).
// ===========================================================================

__device__ __forceinline__ void batch16(unsigned int* lbase,
                                        float4 va, float4 vb,
                                        float4 vc, float4 vd) {
    const float f[16] = {va.x, va.y, va.z, va.w, vb.x, vb.y, vb.z, vb.w,
                         vc.x, vc.y, vc.z, vc.w, vd.x, vd.y, vd.z, vd.w};
    int w[16];            // word offset within lane's hist region (0..63)*64
    unsigned int inc[16];
    unsigned int r[16];
    #pragma unroll
    for (int j = 0; j < 16; ++j) {
        const int b = (int)fminf(fmaxf(f[j], 0.f), 255.f);  // trunc==floor
        w[j] = (b >> 2) * 64;
        inc[j] = 1u << ((b & 3) << 3);
    }
    // 16 scattered ds_reads issued back-to-back (bank = lane&31, conflict-free)
    #pragma unroll
    for (int j = 0; j < 16; ++j) r[j] = lbase[w[j]];
    // Triangular forward-merge: same-word duplicates accumulate into the
    // highest slot; earlier slots write back their original (stale) word and
    // are overwritten by the later full write (same-wave program order).
    #pragma unroll
    for (int j = 0; j < 16; ++j) {
        #pragma unroll
        for (int k = j + 1; k < 16; ++k) {
            if (w[j] == w[k]) { inc[k] += inc[j]; inc[j] = 0; }
        }
    }
    #pragma unroll
    for (int j = 0; j < 16; ++j) lbase[w[j]] = r[j] + inc[j];
}

__global__ __launch_bounds__(THREADS) void hist_kernel(
    const float* __restrict__ a, const float* __restrict__ b,
    unsigned int* __restrict__ gh) {
    __shared__ unsigned int sh[16384];  // 64 KB: per-(wave,lane) u8x4 hists
    const int tid  = threadIdx.x;
    const int wave = tid >> 6;
    const int lane = tid & 63;

    uint4* shv = (uint4*)sh;
    #pragma unroll
    for (int i = 0; i < 16; ++i)
        shv[tid + i * THREADS] = make_uint4(0u, 0u, 0u, 0u);
    __syncthreads();

    const int job        = blockIdx.x >> 8;        // 0..5
    const int blockInJob = blockIdx.x & 255;
    const int arr = job / NCH;   // 0 = input, 1 = label
    const int ch  = job % NCH;

    const float4* __restrict__ src = (const float4*)(arr ? b : a);
    // word = wave*4096 + (bin>>2)*64 + lane -> bank = lane&31 (free 2-way)
    unsigned int* const lbase = &sh[wave * 4096 + lane];
    const unsigned pos = ((unsigned)blockInJob << 8) | (unsigned)tid;  // 0..65535

    // 8 iterations x 4 float4 loads: all 4 loads issued before any DS work,
    // then one 16-element dedup+RMW batch.
    for (int it = 0; it < BATCH / 4; ++it) {
        const int bt = it << 2;
        const float4 v0 = src[(unsigned)(((bt + 0) * NCH + ch) << 16) | pos];
        const float4 v1 = src[(unsigned)(((bt + 1) * NCH + ch) << 16) | pos];
        const float4 v2 = src[(unsigned)(((bt + 2) * NCH + ch) << 16) | pos];
        const float4 v3 = src[(unsigned)(((bt + 3) * NCH + ch) << 16) | pos];
        batch16(lbase, v0, v1, v2, v3);
    }
    __syncthreads();

    // Flush: thread t owns bin t. Sum its byte over 4 waves x 64 lanes,
    // reading uint4 (4 lanes at once), chunk-swizzled to spread banks.
    unsigned int sum = 0;
    const int grp = tid >> 2;          // bin>>2 : word group within lane region
    const int sh8 = (tid & 3) << 3;    // byte shift within word
    #pragma unroll
    for (int w = 0; w < 4; ++w) {
        const unsigned int* base = &sh[w * 4096 + grp * 64];
        #pragma unroll
        for (int c = 0; c < 16; ++c) {
            const int cc = (c + tid) & 15;
            const uint4 q = *(const uint4*)(base + cc * 4);
            sum += ((q.x >> sh8) & 0xFFu) + ((q.y >> sh8) & 0xFFu)
                 + ((q.z >> sh8) & 0xFFu) + ((q.w >> sh8) & 0xFFu);
        }
    }
    atomicAdd(&gh[(arr * NCH + ch) * NBINS + tid], sum);
}

// ---------------------------------------------------------------------------
// Bhattacharyya kernel: 1 block x 256 threads, fp64 reduction. (unchanged)
// ---------------------------------------------------------------------------
__device__ __forceinline__ double block_reduce256(double v, double* sh4) {
    const int t = threadIdx.x;
    const int lane = t & 63, w = t >> 6;
    #pragma unroll
    for (int o = 32; o > 0; o >>= 1) v += __shfl_down(v, o, 64);
    if (lane == 0) sh4[w] = v;
    __syncthreads();
    double r = sh4[0] + sh4[1] + sh4[2] + sh4[3];
    __syncthreads();
    return r;
}

__global__ __launch_bounds__(256) void bhat_kernel(
    const unsigned int* __restrict__ gh, float* __restrict__ out) {
    __shared__ double sh4[4];
    const int t = threadIdx.x;  // bin index
    double result = 0.0;
    #pragma unroll
    for (int ch = 0; ch < NCH; ++ch) {
        const double h1 = (double)gh[ch * NBINS + t];
        const double h2 = (double)gh[(NCH + ch) * NBINS + t];
        const double s  = block_reduce256(sqrt(h1 * h2), sh4);
        const double s1 = block_reduce256(h1, sh4);
        const double s2 = block_reduce256(h2, sh4);
        const double denom = sqrt((s1 / (double)NBINS) * (s2 / (double)NBINS)) * (double)NBINS;
        const double v = 1.0 - s / denom;
        result += sqrt(v > 0.0 ? v : 0.0);
    }
    if (t == 0) out[0] = (float)result;
}

extern "C" void kernel_launch(void* const* d_in, const int* in_sizes, int n_in,
                              void* d_out, int out_size, void* d_ws, size_t ws_size,
                              hipStream_t stream) {
    const float* input = (const float*)d_in[0];
    const float* label = (const float*)d_in[1];
    float* out = (float*)d_out;
    unsigned int* gh = (unsigned int*)d_ws;

    // d_ws is poisoned with 0xAA before every timed launch — zero the hists.
    hipMemsetAsync(gh, 0, NHIST * sizeof(unsigned int), stream);

    hist_kernel<<<6 * BLOCKS_PER_JOB, THREADS, 0, stream>>>(input, label, gh);
    bhat_kernel<<<1, 256, 0, stream>>>(gh, out);
}